// Round 1
// baseline (419.859 us; speedup 1.0000x reference)
//
#include <hip/hip_runtime.h>

#define HP    66
#define QTOT  (HP*HP)          // 4356
#define NWIN  29
#define NW    (NWIN*NWIN)      // 841
#define NS    224
#define KK    7
#define WOFF2 14
#define NZ    15               // dy-chunks for contraction

// ws float layout:
// 0        : ye66   8*QTOT   (channel planes, 66x66 zero-padded)
// 8*QTOT   : xe66   8*QTOT
// 16*QTOT  : x66p   8*QTOT
// 24*QTOT  : sqye   QTOT
// 25*QTOT  : sqxe   QTOT
// 26*QTOT  : lt66   QTOT
// 27*QTOT  : n2q    QTOT
// 28*QTOT  : n2db   QTOT
// 29*QTOT  : ltb    QTOT
// 30*QTOT  : dist   NW*QTOT          (later reused as accb2: NZ*56*4096 fits)
// 30*QTOT + NW*QTOT : wf  KK*NW*QTOT (scattered weights -> box-summed in place)

__global__ __launch_bounds__(256) void k_prep1(const float* __restrict__ x,
    const float* __restrict__ xe, const float* __restrict__ ye,
    const float* __restrict__ lt, float* __restrict__ ws) {
  int p = blockIdx.x * 256 + threadIdx.x;
  if (p >= QTOT) return;
  int i = p / HP, j = p % HP;
  bool in = (i >= 1 && i < HP-1 && j >= 1 && j < HP-1);
  int src = (i-1)*64 + (j-1);
  float* ye66 = ws;
  float* xe66 = ws + 8*QTOT;
  float* x66p = ws + 16*QTOT;
  float sy = 0.f, sx = 0.f;
#pragma unroll
  for (int e = 0; e < 8; ++e) {
    float vy = in ? ye[e*4096 + src] : 0.f;
    float vx = in ? xe[e*4096 + src] : 0.f;
    float vv = in ? x [e*4096 + src] : 0.f;
    ye66[e*QTOT + p] = vy;
    xe66[e*QTOT + p] = vx;
    x66p[e*QTOT + p] = vv;
    sy += vy*vy; sx += vx*vx;
  }
  ws[24*QTOT + p] = sy;
  ws[25*QTOT + p] = sx;
  ws[26*QTOT + p] = in ? lt[src] : 0.f;
}

// patch box (window [i-5, i+4]) of sqye/sqxe/lt66
__global__ __launch_bounds__(256) void k_prep2(float* __restrict__ ws) {
  int p = blockIdx.x * 256 + threadIdx.x;
  if (p >= QTOT) return;
  int i = p / HP, j = p % HP;
  const float* sqye = ws + 24*QTOT;
  const float* sqxe = ws + 25*QTOT;
  const float* lt66 = ws + 26*QTOT;
  float a = 0.f, b = 0.f, c = 0.f;
  for (int u = -5; u <= 4; ++u) {
    int ii = i + u; if (ii < 0 || ii >= HP) continue;
    for (int v = -5; v <= 4; ++v) {
      int jj = j + v; if (jj < 0 || jj >= HP) continue;
      int o = ii*HP + jj;
      a += sqye[o]; b += sqxe[o]; c += lt66[o];
    }
  }
  ws[27*QTOT + p] = a;
  ws[28*QTOT + p] = b;
  ws[29*QTOT + p] = c * 0.01f;   // /(PS*PS)
}

// one block per shift w: dist plane [w][q]
__global__ __launch_bounds__(256) void k_dist(const float* __restrict__ ws,
                                              float* __restrict__ dist) {
  __shared__ float s[QTOT];
  __shared__ float h[QTOT];
  int w = blockIdx.x;
  int dy = w / NWIN - WOFF2, dx = w % NWIN - WOFF2;
  const float* ye66 = ws;
  const float* xe66 = ws + 8*QTOT;
  const float* n2q  = ws + 27*QTOT;
  const float* n2db = ws + 28*QTOT;
  for (int p = threadIdx.x; p < QTOT; p += 256) {
    int i = p / HP, j = p % HP;
    int ii = i + dy, jj = j + dx;
    float sv = 0.f;
    if (ii >= 0 && ii < HP && jj >= 0 && jj < HP) {
      int p2 = ii*HP + jj;
#pragma unroll
      for (int e = 0; e < 8; ++e) sv += ye66[e*QTOT + p] * xe66[e*QTOT + p2];
    }
    s[p] = sv;
  }
  __syncthreads();
  for (int p = threadIdx.x; p < QTOT; p += 256) {
    int i = p / HP, j = p % HP;
    float hv = 0.f;
#pragma unroll
    for (int v = -5; v <= 4; ++v) {
      int jj = j + v;
      if (jj >= 0 && jj < HP) hv += s[i*HP + jj];
    }
    h[p] = hv;
  }
  __syncthreads();
  for (int p = threadIdx.x; p < QTOT; p += 256) {
    int i = p / HP, j = p % HP;
    float cr = 0.f;
#pragma unroll
    for (int u = -5; u <= 4; ++u) {
      int ii = i + u;
      if (ii >= 0 && ii < HP) cr += h[ii*HP + j];
    }
    int ii = i + dy, jj = j + dx;
    bool valid = (ii >= 0 && ii < HP && jj >= 0 && jj < HP);
    float dv = 1e10f;
    if (valid && !(dy == 0 && dx == 0))
      dv = n2q[p] + n2db[ii*HP + jj] - 2.f * cr;
    dist[w*QTOT + p] = dv;
  }
}

// one block per query: exact top-224 (radix select on monotone keys) +
// 7-round softmax chain, scatter weights into wf[k][w][q]
__global__ __launch_bounds__(256) void k_select(const float* __restrict__ ws,
    const float* __restrict__ dist, float* __restrict__ wf) {
  __shared__ float    dl[NW];
  __shared__ unsigned ku[NW];
  __shared__ int      ired[256];
  __shared__ int      selw[NS];
  __shared__ float    red[256];
  __shared__ int      scnt;
  int q = blockIdx.x, tid = threadIdx.x;

  for (int w = tid; w < NW; w += 256) {
    float d = dist[w*QTOT + q];
    dl[w] = d;
    unsigned u = __float_as_uint(d);
    ku[w] = (u & 0x80000000u) ? ~u : (u | 0x80000000u);
  }
  __syncthreads();

  // radix k-th smallest (k = NS, 1-indexed)
  unsigned P = 0; int need = NS;
  for (int b = 31; b >= 0; --b) {
    if (tid == 0) scnt = 0;
    __syncthreads();
    int lc = 0;
#pragma unroll
    for (int t = 0; t < 4; ++t) {
      int w = tid + t*256;
      bool pr = (w < NW) && ((ku[w] >> b) == (P >> b));
      unsigned long long bal = __ballot(pr);
      if ((tid & 63) == 0) lc += __popcll(bal);
    }
    if ((tid & 63) == 0) atomicAdd(&scnt, lc);
    __syncthreads();
    int c = scnt;
    if (c < need) { need -= c; P |= (1u << b); }
    __syncthreads();
  }

  // deterministic compaction: strict-less elements, then equals by index
  int myless = 0;
#pragma unroll
  for (int t = 0; t < 4; ++t) {
    int w = tid + t*256;
    if (w < NW && ku[w] < P) myless++;
  }
  ired[tid] = myless;
  __syncthreads();
  for (int off = 1; off < 256; off <<= 1) {
    int v = (tid >= off) ? ired[tid - off] : 0;
    __syncthreads();
    ired[tid] += v;
    __syncthreads();
  }
  int base = ired[tid] - myless;
  int L = ired[255];
#pragma unroll
  for (int t = 0; t < 4; ++t) {
    int w = tid + t*256;
    if (w < NW && ku[w] < P) selw[base++] = w;
  }
  int tneed = NS - L;
  for (int t = 0; t < 4; ++t) {
    int w = tid + t*256;
    if (w < NW && ku[w] == P) {
      int r = 0;
      for (int v = 0; v < w; ++v) r += (ku[v] == P);
      if (r < tneed) selw[L + r] = w;
    }
  }
  __syncthreads();

  const float* ltb = ws + 29*QTOT;
  float tE = __expf(ltb[q]);
  float l = 0.f; int myw = -1;
  if (tid < NS) { myw = selw[tid]; l = -dl[myw] / tE; }
  for (int k = 0; k < KK; ++k) {
    red[tid] = (tid < NS) ? l : -3.0e38f;
    __syncthreads();
    for (int s2 = 128; s2 > 0; s2 >>= 1) {
      if (tid < s2) red[tid] = fmaxf(red[tid], red[tid + s2]);
      __syncthreads();
    }
    float m = red[0];
    __syncthreads();
    float e = (tid < NS) ? __expf(l - m) : 0.f;
    red[tid] = e;
    __syncthreads();
    for (int s2 = 128; s2 > 0; s2 >>= 1) {
      if (tid < s2) red[tid] += red[tid + s2];
      __syncthreads();
    }
    float den = red[0];
    __syncthreads();
    if (tid < NS) {
      float wgt = e / den;
      wf[(k*NW + myw)*QTOT + q] = wgt;
      l += __logf(fmaxf(1.f - wgt, 1e-6f));
    }
  }
}

// in-place REFLECTED 10x10 box (offsets -4..+5) over query space, per (k,w) plane
__global__ __launch_bounds__(256) void k_boxw(float* __restrict__ wf) {
  __shared__ float a[QTOT];
  __shared__ float b2[QTOT];
  float* plane = wf + (size_t)blockIdx.x * QTOT;
  for (int p = threadIdx.x; p < QTOT; p += 256) a[p] = plane[p];
  __syncthreads();
  for (int p = threadIdx.x; p < QTOT; p += 256) {
    int i = p / HP, j = p % HP;
    float s = 0.f;
#pragma unroll
    for (int v = -4; v <= 5; ++v) {
      int jj = j + v;
      if (jj >= 0 && jj < HP) s += a[i*HP + jj];
    }
    b2[p] = s;
  }
  __syncthreads();
  for (int p = threadIdx.x; p < QTOT; p += 256) {
    int i = p / HP, j = p % HP;
    float s = 0.f;
#pragma unroll
    for (int u = -4; u <= 5; ++u) {
      int ii = i + u;
      if (ii >= 0 && ii < HP) s += b2[ii*HP + j];
    }
    plane[p] = s;
  }
}

// out_acc[k,c,I,J] partials: grid (16 tiles, NZ dy-chunks); thread = one output pixel,
// 56 accumulators; x region staged in LDS channel-planes (conflict-free b32 reads)
__global__ __launch_bounds__(256) void k_contract(const float* __restrict__ ws,
    const float* __restrict__ wf, float* __restrict__ accb2) {
  __shared__ float xt[8][18][44];
  int t = blockIdx.x, z = blockIdx.y, tid = threadIdx.x;
  int I0 = (t >> 2) * 16, J0 = (t & 3) * 16;
  int dylo = -WOFF2 + 2*z;
  int dyhi = (z == NZ-1) ? WOFF2 : (dylo + 1);
  int NRr = 16 + (dyhi - dylo);       // 17 (z<14) or 16 (z=14)
  int gy0 = I0 + 1 + dylo, gx0 = J0 - 13;
  const float* x66p = ws + 16*QTOT;
  for (int idx = tid; idx < 8*NRr*44; idx += 256) {
    int c = idx / (NRr*44);
    int rem = idx % (NRr*44);
    int r = rem / 44, cc = rem % 44;
    int gy = gy0 + r, gx = gx0 + cc;
    float v = 0.f;
    if (gy >= 0 && gy < HP && gx >= 0 && gx < HP) v = x66p[c*QTOT + gy*HP + gx];
    xt[c][r][cc] = v;
  }
  __syncthreads();
  int il = tid >> 4, jl = tid & 15;
  int I = I0 + 1 + il, J = J0 + 1 + jl;
  int pix = I*HP + J;
  float acc[KK][8];
#pragma unroll
  for (int k = 0; k < KK; ++k)
#pragma unroll
    for (int c = 0; c < 8; ++c) acc[k][c] = 0.f;
  int wlo = (dylo + WOFF2) * NWIN, whi = (dyhi + WOFF2 + 1) * NWIN;
  for (int w = wlo; w < whi; ++w) {
    int dyw = w / NWIN - WOFF2, dxw = w % NWIN - WOFF2;
    int r = il + (dyw - dylo), col = jl + dxw + 14;
    float xv[8];
#pragma unroll
    for (int c = 0; c < 8; ++c) xv[c] = xt[c][r][col];
#pragma unroll
    for (int k = 0; k < KK; ++k) {
      float wsv = wf[((size_t)(k*NW + w))*QTOT + pix];
#pragma unroll
      for (int c = 0; c < 8; ++c) acc[k][c] += wsv * xv[c];
    }
  }
  int px64 = (I-1)*64 + (J-1);
#pragma unroll
  for (int k = 0; k < KK; ++k)
#pragma unroll
    for (int c = 0; c < 8; ++c)
      accb2[((z*56 + k*8 + c)*4096) + px64] = acc[k][c];
}

__global__ __launch_bounds__(256) void k_final(const float* __restrict__ y,
    const float* __restrict__ accb2, float* __restrict__ out) {
  int idx = blockIdx.x * 256 + threadIdx.x;   // < 262144
  int ch = idx >> 12, px = idx & 4095;
  if (ch < 8) { out[idx] = y[ch*4096 + px]; return; }
  int kc = ch - 8, c = kc & 7;
  int i = px >> 6, j = px & 63;
  int I = i + 1, J = j + 1;
  int cy = min(I+5, HP-1) - max(I-4, 0) + 1;
  int cx = min(J+5, HP-1) - max(J-4, 0) + 1;
  float s = 0.f;
  for (int z = 0; z < NZ; ++z) s += accb2[(z*56 + kc)*4096 + px];
  out[idx] = s / (float)(cy*cx) - y[c*4096 + px];
}

extern "C" void kernel_launch(void* const* d_in, const int* in_sizes, int n_in,
                              void* d_out, int out_size, void* d_ws, size_t ws_size,
                              hipStream_t stream) {
  const float* x  = (const float*)d_in[0];
  const float* xe = (const float*)d_in[1];
  const float* ye = (const float*)d_in[2];
  const float* y  = (const float*)d_in[3];
  const float* lt = (const float*)d_in[4];
  float* ws   = (float*)d_ws;
  float* dist = ws + 30*QTOT;
  float* wf   = dist + (size_t)NW*QTOT;
  float* accb2 = dist;                 // dist dead after k_select; reuse
  float* out = (float*)d_out;

  k_prep1<<<(QTOT + 255)/256, 256, 0, stream>>>(x, xe, ye, lt, ws);
  k_prep2<<<(QTOT + 255)/256, 256, 0, stream>>>(ws);
  hipMemsetAsync(wf, 0, (size_t)KK*NW*QTOT*sizeof(float), stream);
  k_dist<<<NW, 256, 0, stream>>>(ws, dist);
  k_select<<<QTOT, 256, 0, stream>>>(ws, dist, wf);
  k_boxw<<<KK*NW, 256, 0, stream>>>(wf);
  k_contract<<<dim3(16, NZ), 256, 0, stream>>>(ws, wf, accb2);
  k_final<<<out_size/256, 256, 0, stream>>>(y, accb2, out);
}

// Round 2
// 291.275 us; speedup vs baseline: 1.4415x; 1.4415x over previous
//
#include <hip/hip_runtime.h>
#include <hip/hip_bf16.h>

#define HP    66
#define QTOT  (HP*HP)          // 4356
#define NWIN  29
#define NW    (NWIN*NWIN)      // 841
#define KK    7
#define WOFF2 14
#define NZ    15               // dy-chunks for contraction
#define NIT   53               // ceil(841*16/256)

// ws float layout:
// 0        : ye66   8*QTOT   (channel planes, 66x66 zero-padded)
// 8*QTOT   : xe66   8*QTOT
// 16*QTOT  : x66p   8*QTOT
// 24*QTOT  : sqye   QTOT
// 25*QTOT  : sqxe   QTOT
// 26*QTOT  : lt66   QTOT
// 27*QTOT  : n2q    QTOT
// 28*QTOT  : n2db   QTOT
// 29*QTOT  : ltb    QTOT
// 30*QTOT  : dist   NW*QTOT f32      (later reused as accb2: NZ*56*4096 fits)
// 30*QTOT + NW*QTOT : wf  KK*NW*QTOT bf16 (dense weight field, boxed in place)

__global__ __launch_bounds__(256) void k_prep1(const float* __restrict__ x,
    const float* __restrict__ xe, const float* __restrict__ ye,
    const float* __restrict__ lt, float* __restrict__ ws) {
  int p = blockIdx.x * 256 + threadIdx.x;
  if (p >= QTOT) return;
  int i = p / HP, j = p % HP;
  bool in = (i >= 1 && i < HP-1 && j >= 1 && j < HP-1);
  int src = (i-1)*64 + (j-1);
  float* ye66 = ws;
  float* xe66 = ws + 8*QTOT;
  float* x66p = ws + 16*QTOT;
  float sy = 0.f, sx = 0.f;
#pragma unroll
  for (int e = 0; e < 8; ++e) {
    float vy = in ? ye[e*4096 + src] : 0.f;
    float vx = in ? xe[e*4096 + src] : 0.f;
    float vv = in ? x [e*4096 + src] : 0.f;
    ye66[e*QTOT + p] = vy;
    xe66[e*QTOT + p] = vx;
    x66p[e*QTOT + p] = vv;
    sy += vy*vy; sx += vx*vx;
  }
  ws[24*QTOT + p] = sy;
  ws[25*QTOT + p] = sx;
  ws[26*QTOT + p] = in ? lt[src] : 0.f;
}

// patch box (window [i-5, i+4]) of sqye/sqxe/lt66
__global__ __launch_bounds__(256) void k_prep2(float* __restrict__ ws) {
  int p = blockIdx.x * 256 + threadIdx.x;
  if (p >= QTOT) return;
  int i = p / HP, j = p % HP;
  const float* sqye = ws + 24*QTOT;
  const float* sqxe = ws + 25*QTOT;
  const float* lt66 = ws + 26*QTOT;
  float a = 0.f, b = 0.f, c = 0.f;
  for (int u = -5; u <= 4; ++u) {
    int ii = i + u; if (ii < 0 || ii >= HP) continue;
    for (int v = -5; v <= 4; ++v) {
      int jj = j + v; if (jj < 0 || jj >= HP) continue;
      int o = ii*HP + jj;
      a += sqye[o]; b += sqxe[o]; c += lt66[o];
    }
  }
  ws[27*QTOT + p] = a;
  ws[28*QTOT + p] = b;
  ws[29*QTOT + p] = c * 0.01f;   // /(PS*PS)
}

// one block per shift w: dist plane [w][q]
__global__ __launch_bounds__(256) void k_dist(const float* __restrict__ ws,
                                              float* __restrict__ dist) {
  __shared__ float s[QTOT];
  __shared__ float h[QTOT];
  int w = blockIdx.x;
  int dy = w / NWIN - WOFF2, dx = w % NWIN - WOFF2;
  const float* ye66 = ws;
  const float* xe66 = ws + 8*QTOT;
  const float* n2q  = ws + 27*QTOT;
  const float* n2db = ws + 28*QTOT;
  for (int p = threadIdx.x; p < QTOT; p += 256) {
    int i = p / HP, j = p % HP;
    int ii = i + dy, jj = j + dx;
    float sv = 0.f;
    if (ii >= 0 && ii < HP && jj >= 0 && jj < HP) {
      int p2 = ii*HP + jj;
#pragma unroll
      for (int e = 0; e < 8; ++e) sv += ye66[e*QTOT + p] * xe66[e*QTOT + p2];
    }
    s[p] = sv;
  }
  __syncthreads();
  for (int p = threadIdx.x; p < QTOT; p += 256) {
    int i = p / HP, j = p % HP;
    float hv = 0.f;
#pragma unroll
    for (int v = -5; v <= 4; ++v) {
      int jj = j + v;
      if (jj >= 0 && jj < HP) hv += s[i*HP + jj];
    }
    h[p] = hv;
  }
  __syncthreads();
  for (int p = threadIdx.x; p < QTOT; p += 256) {
    int i = p / HP, j = p % HP;
    float cr = 0.f;
#pragma unroll
    for (int u = -5; u <= 4; ++u) {
      int ii = i + u;
      if (ii >= 0 && ii < HP) cr += h[ii*HP + j];
    }
    int ii = i + dy, jj = j + dx;
    bool valid = (ii >= 0 && ii < HP && jj >= 0 && jj < HP);
    float dv = 1e10f;
    if (valid && !(dy == 0 && dx == 0))
      dv = n2q[p] + n2db[ii*HP + jj] - 2.f * cr;
    dist[w*QTOT + p] = dv;
  }
}

// 16 queries per block; full-841 softmax chain (== top-224: tail weights
// underflow to exactly 0 in f32 since temp~1 and dist gaps are O(100)).
// Logits live in registers (53/thread); dense bf16 writes in [k][w][q] layout.
__global__ __launch_bounds__(256) void k_weights(const float* __restrict__ ws,
    const float* __restrict__ dist, __hip_bfloat16* __restrict__ wf) {
  __shared__ float red[256];
  __shared__ float mh[16], dh[16];
  int tid = threadIdx.x;
  int q0 = blockIdx.x * 16;
  int qq = tid & 15;
  int q = q0 + qq;
  bool qok = q < QTOT;
  int qs = qok ? q : (QTOT - 1);
  int wbase = tid >> 4;          // 0..15
  float invT = __expf(-ws[29*QTOT + qs]);   // 1/exp(ltb)
  float lv[NIT], ev[NIT];
#pragma unroll
  for (int it = 0; it < NIT; ++it) {
    int w = wbase + it*16;
    lv[it] = (qok && w < NW) ? (-dist[w*QTOT + qs] * invT) : -3.0e38f;
  }
  for (int k = 0; k < KK; ++k) {
    float pm = -3.0e38f;
#pragma unroll
    for (int it = 0; it < NIT; ++it) pm = fmaxf(pm, lv[it]);
    red[tid] = pm;
    __syncthreads();
    for (int s = 128; s >= 16; s >>= 1) {
      if (tid < s) red[tid] = fmaxf(red[tid], red[tid + s]);
      __syncthreads();
    }
    if (tid < 16) mh[tid] = red[tid];
    __syncthreads();
    float m = mh[qq];
    float psum = 0.f;
#pragma unroll
    for (int it = 0; it < NIT; ++it) {
      float e = __expf(lv[it] - m);
      ev[it] = e;
      psum += e;
    }
    __syncthreads();
    red[tid] = psum;
    __syncthreads();
    for (int s = 128; s >= 16; s >>= 1) {
      if (tid < s) red[tid] += red[tid + s];
      __syncthreads();
    }
    if (tid < 16) dh[tid] = 1.0f / red[tid];
    __syncthreads();
    float invden = dh[qq];
#pragma unroll
    for (int it = 0; it < NIT; ++it) {
      int w = wbase + it*16;
      if (qok && w < NW) {
        float wgt = ev[it] * invden;
        wf[((size_t)(k*NW + w))*QTOT + q] = __float2bfloat16(wgt);
        if (k < KK-1) lv[it] += __logf(fmaxf(1.f - wgt, 1e-6f));
      }
    }
    __syncthreads();
  }
}

// in-place REFLECTED 10x10 box (offsets -4..+5) over query space, per (k,w) plane
__global__ __launch_bounds__(256) void k_boxw(__hip_bfloat16* __restrict__ wf) {
  __shared__ float a[QTOT];
  __shared__ float b2[QTOT];
  __hip_bfloat16* plane = wf + (size_t)blockIdx.x * QTOT;
  for (int p = threadIdx.x; p < QTOT; p += 256) a[p] = __bfloat162float(plane[p]);
  __syncthreads();
  for (int p = threadIdx.x; p < QTOT; p += 256) {
    int i = p / HP, j = p % HP;
    float s = 0.f;
#pragma unroll
    for (int v = -4; v <= 5; ++v) {
      int jj = j + v;
      if (jj >= 0 && jj < HP) s += a[i*HP + jj];
    }
    b2[p] = s;
  }
  __syncthreads();
  for (int p = threadIdx.x; p < QTOT; p += 256) {
    int i = p / HP, j = p % HP;
    float s = 0.f;
#pragma unroll
    for (int u = -4; u <= 5; ++u) {
      int ii = i + u;
      if (ii >= 0 && ii < HP) s += b2[ii*HP + j];
    }
    plane[p] = __float2bfloat16(s);
  }
}

// out_acc[k,c,I,J] partials: grid (16 tiles, NZ dy-chunks); thread = one output pixel,
// 56 accumulators; x region staged in LDS channel-planes
__global__ __launch_bounds__(256) void k_contract(const float* __restrict__ ws,
    const __hip_bfloat16* __restrict__ wf, float* __restrict__ accb2) {
  __shared__ float xt[8][18][44];
  int t = blockIdx.x, z = blockIdx.y, tid = threadIdx.x;
  int I0 = (t >> 2) * 16, J0 = (t & 3) * 16;
  int dylo = -WOFF2 + 2*z;
  int dyhi = (z == NZ-1) ? WOFF2 : (dylo + 1);
  int NRr = 16 + (dyhi - dylo);       // 17 (z<14) or 16 (z=14)
  int gy0 = I0 + 1 + dylo, gx0 = J0 - 13;
  const float* x66p = ws + 16*QTOT;
  for (int idx = tid; idx < 8*NRr*44; idx += 256) {
    int c = idx / (NRr*44);
    int rem = idx % (NRr*44);
    int r = rem / 44, cc = rem % 44;
    int gy = gy0 + r, gx = gx0 + cc;
    float v = 0.f;
    if (gy >= 0 && gy < HP && gx >= 0 && gx < HP) v = x66p[c*QTOT + gy*HP + gx];
    xt[c][r][cc] = v;
  }
  __syncthreads();
  int il = tid >> 4, jl = tid & 15;
  int I = I0 + 1 + il, J = J0 + 1 + jl;
  int pix = I*HP + J;
  float acc[KK][8];
#pragma unroll
  for (int k = 0; k < KK; ++k)
#pragma unroll
    for (int c = 0; c < 8; ++c) acc[k][c] = 0.f;
  int wlo = (dylo + WOFF2) * NWIN, whi = (dyhi + WOFF2 + 1) * NWIN;
  for (int w = wlo; w < whi; ++w) {
    int dyw = w / NWIN - WOFF2, dxw = w % NWIN - WOFF2;
    int r = il + (dyw - dylo), col = jl + dxw + 14;
    float xv[8];
#pragma unroll
    for (int c = 0; c < 8; ++c) xv[c] = xt[c][r][col];
#pragma unroll
    for (int k = 0; k < KK; ++k) {
      float wsv = __bfloat162float(wf[((size_t)(k*NW + w))*QTOT + pix]);
#pragma unroll
      for (int c = 0; c < 8; ++c) acc[k][c] += wsv * xv[c];
    }
  }
  int px64 = (I-1)*64 + (J-1);
#pragma unroll
  for (int k = 0; k < KK; ++k)
#pragma unroll
    for (int c = 0; c < 8; ++c)
      accb2[((z*56 + k*8 + c)*4096) + px64] = acc[k][c];
}

__global__ __launch_bounds__(256) void k_final(const float* __restrict__ y,
    const float* __restrict__ accb2, float* __restrict__ out) {
  int idx = blockIdx.x * 256 + threadIdx.x;   // < 262144
  int ch = idx >> 12, px = idx & 4095;
  if (ch < 8) { out[idx] = y[ch*4096 + px]; return; }
  int kc = ch - 8, c = kc & 7;
  int i = px >> 6, j = px & 63;
  int I = i + 1, J = j + 1;
  int cy = min(I+5, HP-1) - max(I-4, 0) + 1;
  int cx = min(J+5, HP-1) - max(J-4, 0) + 1;
  float s = 0.f;
  for (int z = 0; z < NZ; ++z) s += accb2[(z*56 + kc)*4096 + px];
  out[idx] = s / (float)(cy*cx) - y[c*4096 + px];
}

extern "C" void kernel_launch(void* const* d_in, const int* in_sizes, int n_in,
                              void* d_out, int out_size, void* d_ws, size_t ws_size,
                              hipStream_t stream) {
  const float* x  = (const float*)d_in[0];
  const float* xe = (const float*)d_in[1];
  const float* ye = (const float*)d_in[2];
  const float* y  = (const float*)d_in[3];
  const float* lt = (const float*)d_in[4];
  float* ws   = (float*)d_ws;
  float* dist = ws + 30*QTOT;
  __hip_bfloat16* wf = (__hip_bfloat16*)(dist + (size_t)NW*QTOT);
  float* accb2 = dist;                 // dist dead after k_weights; reuse
  float* out = (float*)d_out;

  k_prep1<<<(QTOT + 255)/256, 256, 0, stream>>>(x, xe, ye, lt, ws);
  k_prep2<<<(QTOT + 255)/256, 256, 0, stream>>>(ws);
  k_dist<<<NW, 256, 0, stream>>>(ws, dist);
  k_weights<<<(QTOT + 15)/16, 256, 0, stream>>>(ws, dist, wf);
  k_boxw<<<KK*NW, 256, 0, stream>>>(wf);
  k_contract<<<dim3(16, NZ), 256, 0, stream>>>(ws, wf, accb2);
  k_final<<<out_size/256, 256, 0, stream>>>(y, accb2, out);
}

// Round 3
// 236.313 us; speedup vs baseline: 1.7767x; 1.2326x over previous
//
#include <hip/hip_runtime.h>
#include <hip/hip_bf16.h>

#define HP    66
#define QTOT  (HP*HP)          // 4356
#define LSTR  67               // padded LDS row stride (odd bank step)
#define NWIN  29
#define NW    (NWIN*NWIN)      // 841
#define KK    7
#define WOFF2 14
#define NZ    15               // dy-chunks for contraction
#define NIT   53               // ceil(841*16/256)
#define NSEG  264              // 66 rows/cols x 4 segments of <=17

// ws float layout:
// 0        : ye66   8*QTOT   (channel planes, 66x66 zero-padded)
// 8*QTOT   : xe66   8*QTOT
// 16*QTOT  : x66p   8*QTOT
// 24*QTOT  : sqye   QTOT
// 25*QTOT  : sqxe   QTOT
// 26*QTOT  : lt66   QTOT
// 27*QTOT  : n2q    QTOT
// 28*QTOT  : n2db   QTOT
// 29*QTOT  : ltb    QTOT
// 30*QTOT  : dist   NW*QTOT f32      (later reused as accb2: NZ*56*4096 fits)
// 30*QTOT + NW*QTOT : wf  KK*NW*QTOT bf16 (dense weight field, boxed in place)

__global__ __launch_bounds__(256) void k_prep1(const float* __restrict__ x,
    const float* __restrict__ xe, const float* __restrict__ ye,
    const float* __restrict__ lt, float* __restrict__ ws) {
  int p = blockIdx.x * 256 + threadIdx.x;
  if (p >= QTOT) return;
  int i = p / HP, j = p % HP;
  bool in = (i >= 1 && i < HP-1 && j >= 1 && j < HP-1);
  int src = (i-1)*64 + (j-1);
  float* ye66 = ws;
  float* xe66 = ws + 8*QTOT;
  float* x66p = ws + 16*QTOT;
  float sy = 0.f, sx = 0.f;
#pragma unroll
  for (int e = 0; e < 8; ++e) {
    float vy = in ? ye[e*4096 + src] : 0.f;
    float vx = in ? xe[e*4096 + src] : 0.f;
    float vv = in ? x [e*4096 + src] : 0.f;
    ye66[e*QTOT + p] = vy;
    xe66[e*QTOT + p] = vx;
    x66p[e*QTOT + p] = vv;
    sy += vy*vy; sx += vx*vx;
  }
  ws[24*QTOT + p] = sy;
  ws[25*QTOT + p] = sx;
  ws[26*QTOT + p] = in ? lt[src] : 0.f;
}

// patch box (window [i-5, i+4]) of sqye/sqxe/lt66
__global__ __launch_bounds__(256) void k_prep2(float* __restrict__ ws) {
  int p = blockIdx.x * 256 + threadIdx.x;
  if (p >= QTOT) return;
  int i = p / HP, j = p % HP;
  const float* sqye = ws + 24*QTOT;
  const float* sqxe = ws + 25*QTOT;
  const float* lt66 = ws + 26*QTOT;
  float a = 0.f, b = 0.f, c = 0.f;
  for (int u = -5; u <= 4; ++u) {
    int ii = i + u; if (ii < 0 || ii >= HP) continue;
    for (int v = -5; v <= 4; ++v) {
      int jj = j + v; if (jj < 0 || jj >= HP) continue;
      int o = ii*HP + jj;
      a += sqye[o]; b += sqxe[o]; c += lt66[o];
    }
  }
  ws[27*QTOT + p] = a;
  ws[28*QTOT + p] = b;
  ws[29*QTOT + p] = c * 0.01f;   // /(PS*PS)
}

// one block per shift w: dist plane [w][q]. Box via sliding-window running sums.
__global__ __launch_bounds__(256) void k_dist(const float* __restrict__ ws,
                                              float* __restrict__ dist) {
  __shared__ float s[HP*LSTR];
  __shared__ float h[HP*LSTR];
  int w = blockIdx.x, tid = threadIdx.x;
  int dy = w / NWIN - WOFF2, dx = w % NWIN - WOFF2;
  const float* ye66 = ws;
  const float* xe66 = ws + 8*QTOT;
  const float* n2q  = ws + 27*QTOT;
  const float* n2db = ws + 28*QTOT;
  for (int p = tid; p < QTOT; p += 256) {
    int i = p / HP, j = p % HP;
    int ii = i + dy, jj = j + dx;
    float sv = 0.f;
    if (ii >= 0 && ii < HP && jj >= 0 && jj < HP) {
      int p2 = ii*HP + jj;
#pragma unroll
      for (int e = 0; e < 8; ++e) sv += ye66[e*QTOT + p] * xe66[e*QTOT + p2];
    }
    s[i*LSTR + j] = sv;
  }
  __syncthreads();
  // horizontal box, window [-5, +4]
  for (int t = tid; t < NSEG; t += 256) {
    int row = t % HP, seg = t / HP;
    int c0 = seg * 17, c1 = min(c0 + 17, HP);
    const float* ar = s + row*LSTR;
    float* hr = h + row*LSTR;
    float sum = 0.f;
    for (int j = max(c0-5, 0); j <= min(c0+3, HP-1); ++j) sum += ar[j];
    for (int j = c0; j < c1; ++j) {
      if (j+4 < HP) sum += ar[j+4];
      hr[j] = sum;
      if (j-5 >= 0) sum -= ar[j-5];
    }
  }
  __syncthreads();
  // vertical box, window [-5, +4], + dist epilogue
  for (int t = tid; t < NSEG; t += 256) {
    int col = t % HP, seg = t / HP;
    int r0 = seg * 17, r1 = min(r0 + 17, HP);
    float sum = 0.f;
    for (int i = max(r0-5, 0); i <= min(r0+3, HP-1); ++i) sum += h[i*LSTR + col];
    for (int i = r0; i < r1; ++i) {
      if (i+4 < HP) sum += h[(i+4)*LSTR + col];
      float cr = sum;
      int p = i*HP + col;
      int ii = i + dy, jj = col + dx;
      bool valid = (ii >= 0 && ii < HP && jj >= 0 && jj < HP);
      float dv = 1e10f;
      if (valid && !(dy == 0 && dx == 0))
        dv = n2q[p] + n2db[ii*HP + jj] - 2.f * cr;
      dist[w*QTOT + p] = dv;
      if (i-5 >= 0) sum -= h[(i-5)*LSTR + col];
    }
  }
}

// 16 queries per block; full-841 softmax chain (== top-224: tail weights
// underflow to exactly 0 in f32 since temp~1 and dist gaps are O(100)).
__global__ __launch_bounds__(256) void k_weights(const float* __restrict__ ws,
    const float* __restrict__ dist, __hip_bfloat16* __restrict__ wf) {
  __shared__ float red[256];
  __shared__ float mh[16], dh[16];
  int tid = threadIdx.x;
  int q0 = blockIdx.x * 16;
  int qq = tid & 15;
  int q = q0 + qq;
  bool qok = q < QTOT;
  int qs = qok ? q : (QTOT - 1);
  int wbase = tid >> 4;          // 0..15
  float invT = __expf(-ws[29*QTOT + qs]);   // 1/exp(ltb)
  float lv[NIT], ev[NIT];
#pragma unroll
  for (int it = 0; it < NIT; ++it) {
    int w = wbase + it*16;
    lv[it] = (qok && w < NW) ? (-dist[w*QTOT + qs] * invT) : -3.0e38f;
  }
  for (int k = 0; k < KK; ++k) {
    float pm = -3.0e38f;
#pragma unroll
    for (int it = 0; it < NIT; ++it) pm = fmaxf(pm, lv[it]);
    red[tid] = pm;
    __syncthreads();
    for (int s = 128; s >= 16; s >>= 1) {
      if (tid < s) red[tid] = fmaxf(red[tid], red[tid + s]);
      __syncthreads();
    }
    if (tid < 16) mh[tid] = red[tid];
    __syncthreads();
    float m = mh[qq];
    float psum = 0.f;
#pragma unroll
    for (int it = 0; it < NIT; ++it) {
      float e = __expf(lv[it] - m);
      ev[it] = e;
      psum += e;
    }
    __syncthreads();
    red[tid] = psum;
    __syncthreads();
    for (int s = 128; s >= 16; s >>= 1) {
      if (tid < s) red[tid] += red[tid + s];
      __syncthreads();
    }
    if (tid < 16) dh[tid] = 1.0f / red[tid];
    __syncthreads();
    float invden = dh[qq];
#pragma unroll
    for (int it = 0; it < NIT; ++it) {
      int w = wbase + it*16;
      if (qok && w < NW) {
        float wgt = ev[it] * invden;
        wf[((size_t)(k*NW + w))*QTOT + q] = __float2bfloat16(wgt);
        if (k < KK-1) lv[it] += __logf(fmaxf(1.f - wgt, 1e-6f));
      }
    }
    __syncthreads();
  }
}

// in-place REFLECTED 10x10 box (offsets -4..+5), sliding-window separable
__global__ __launch_bounds__(256) void k_boxw(__hip_bfloat16* __restrict__ wf) {
  __shared__ float a[HP*LSTR];
  __shared__ float h[HP*LSTR];
  __hip_bfloat16* plane = wf + (size_t)blockIdx.x * QTOT;
  int tid = threadIdx.x;
  for (int p = tid; p < QTOT; p += 256)
    a[(p/HP)*LSTR + (p%HP)] = __bfloat162float(plane[p]);
  __syncthreads();
  // horizontal, window [-4, +5]
  for (int t = tid; t < NSEG; t += 256) {
    int row = t % HP, seg = t / HP;
    int c0 = seg * 17, c1 = min(c0 + 17, HP);
    const float* ar = a + row*LSTR;
    float* hr = h + row*LSTR;
    float sum = 0.f;
    for (int j = max(c0-4, 0); j <= min(c0+4, HP-1); ++j) sum += ar[j];
    for (int j = c0; j < c1; ++j) {
      if (j+5 < HP) sum += ar[j+5];
      hr[j] = sum;
      if (j-4 >= 0) sum -= ar[j-4];
    }
  }
  __syncthreads();
  // vertical, window [-4, +5], write bf16 back
  for (int t = tid; t < NSEG; t += 256) {
    int col = t % HP, seg = t / HP;
    int r0 = seg * 17, r1 = min(r0 + 17, HP);
    float sum = 0.f;
    for (int i = max(r0-4, 0); i <= min(r0+4, HP-1); ++i) sum += h[i*LSTR + col];
    for (int i = r0; i < r1; ++i) {
      if (i+5 < HP) sum += h[(i+5)*LSTR + col];
      plane[i*HP + col] = __float2bfloat16(sum);
      if (i-4 >= 0) sum -= h[(i-4)*LSTR + col];
    }
  }
}

// out_acc[k,c,I,J] partials: grid (16 tiles, NZ dy-chunks)
__global__ __launch_bounds__(256) void k_contract(const float* __restrict__ ws,
    const __hip_bfloat16* __restrict__ wf, float* __restrict__ accb2) {
  __shared__ float xt[8][18][44];
  int t = blockIdx.x, z = blockIdx.y, tid = threadIdx.x;
  int I0 = (t >> 2) * 16, J0 = (t & 3) * 16;
  int dylo = -WOFF2 + 2*z;
  int dyhi = (z == NZ-1) ? WOFF2 : (dylo + 1);
  int NRr = 16 + (dyhi - dylo);       // 17 (z<14) or 16 (z=14)
  int gy0 = I0 + 1 + dylo, gx0 = J0 - 13;
  const float* x66p = ws + 16*QTOT;
  for (int idx = tid; idx < 8*NRr*44; idx += 256) {
    int c = idx / (NRr*44);
    int rem = idx % (NRr*44);
    int r = rem / 44, cc = rem % 44;
    int gy = gy0 + r, gx = gx0 + cc;
    float v = 0.f;
    if (gy >= 0 && gy < HP && gx >= 0 && gx < HP) v = x66p[c*QTOT + gy*HP + gx];
    xt[c][r][cc] = v;
  }
  __syncthreads();
  int il = tid >> 4, jl = tid & 15;
  int I = I0 + 1 + il, J = J0 + 1 + jl;
  int pix = I*HP + J;
  float acc[KK][8];
#pragma unroll
  for (int k = 0; k < KK; ++k)
#pragma unroll
    for (int c = 0; c < 8; ++c) acc[k][c] = 0.f;
  int wlo = (dylo + WOFF2) * NWIN, whi = (dyhi + WOFF2 + 1) * NWIN;
  for (int w = wlo; w < whi; ++w) {
    int dyw = w / NWIN - WOFF2, dxw = w % NWIN - WOFF2;
    int r = il + (dyw - dylo), col = jl + dxw + 14;
    float xv[8];
#pragma unroll
    for (int c = 0; c < 8; ++c) xv[c] = xt[c][r][col];
#pragma unroll
    for (int k = 0; k < KK; ++k) {
      float wsv = __bfloat162float(wf[((size_t)(k*NW + w))*QTOT + pix]);
#pragma unroll
      for (int c = 0; c < 8; ++c) acc[k][c] += wsv * xv[c];
    }
  }
  int px64 = (I-1)*64 + (J-1);
#pragma unroll
  for (int k = 0; k < KK; ++k)
#pragma unroll
    for (int c = 0; c < 8; ++c)
      accb2[((z*56 + k*8 + c)*4096) + px64] = acc[k][c];
}

__global__ __launch_bounds__(256) void k_final(const float* __restrict__ y,
    const float* __restrict__ accb2, float* __restrict__ out) {
  int idx = blockIdx.x * 256 + threadIdx.x;   // < 262144
  int ch = idx >> 12, px = idx & 4095;
  if (ch < 8) { out[idx] = y[ch*4096 + px]; return; }
  int kc = ch - 8, c = kc & 7;
  int i = px >> 6, j = px & 63;
  int I = i + 1, J = j + 1;
  int cy = min(I+5, HP-1) - max(I-4, 0) + 1;
  int cx = min(J+5, HP-1) - max(J-4, 0) + 1;
  float s = 0.f;
  for (int z = 0; z < NZ; ++z) s += accb2[(z*56 + kc)*4096 + px];
  out[idx] = s / (float)(cy*cx) - y[c*4096 + px];
}

extern "C" void kernel_launch(void* const* d_in, const int* in_sizes, int n_in,
                              void* d_out, int out_size, void* d_ws, size_t ws_size,
                              hipStream_t stream) {
  const float* x  = (const float*)d_in[0];
  const float* xe = (const float*)d_in[1];
  const float* ye = (const float*)d_in[2];
  const float* y  = (const float*)d_in[3];
  const float* lt = (const float*)d_in[4];
  float* ws   = (float*)d_ws;
  float* dist = ws + 30*QTOT;
  __hip_bfloat16* wf = (__hip_bfloat16*)(dist + (size_t)NW*QTOT);
  float* accb2 = dist;                 // dist dead after k_weights; reuse
  float* out = (float*)d_out;

  k_prep1<<<(QTOT + 255)/256, 256, 0, stream>>>(x, xe, ye, lt, ws);
  k_prep2<<<(QTOT + 255)/256, 256, 0, stream>>>(ws);
  k_dist<<<NW, 256, 0, stream>>>(ws, dist);
  k_weights<<<(QTOT + 15)/16, 256, 0, stream>>>(ws, dist, wf);
  k_boxw<<<KK*NW, 256, 0, stream>>>(wf);
  k_contract<<<dim3(16, NZ), 256, 0, stream>>>(ws, wf, accb2);
  k_final<<<out_size/256, 256, 0, stream>>>(y, accb2, out);
}